// Round 2
// baseline (2365.733 us; speedup 1.0000x reference)
//
#include <hip/hip_runtime.h>

// ---------------- problem constants ----------------
constexpr int kB = 128, kP = 196, kT = 20;
constexpr int kVocab = 10000, kEnc = 2048, kEmb = 512, kDec = 512, kAttn = 512;

typedef __bf16 b16x8 __attribute__((ext_vector_type(8)));
typedef __bf16 b16x4 __attribute__((ext_vector_type(4)));
typedef float f32x4 __attribute__((ext_vector_type(4)));
typedef unsigned short u16x4 __attribute__((ext_vector_type(4)));

__device__ __forceinline__ unsigned short f2bf(float f) {
  unsigned int u = __float_as_uint(f);
  u += 0x7fffu + ((u >> 16) & 1u);          // RNE (inputs finite)
  return (unsigned short)(u >> 16);
}
__device__ __forceinline__ float bf2f(unsigned short h) {
  return __uint_as_float(((unsigned int)h) << 16);
}

__device__ __forceinline__ void async16(const void* g, void* l) {
  __builtin_amdgcn_global_load_lds(
      (const __attribute__((address_space(1))) unsigned int*)g,
      (__attribute__((address_space(3))) unsigned int*)l, 16, 0, 0);
}

// =========== 128x128-tile bf16 GEMM, double-buffered (2-phase): C = A[M,K]@W[N,K]^T + bias ===
// 4 waves (2x2), 4x4 acc/wave, BK=32. A AND B staged via global_load_lds, chunk-major LDS
// (slot = chunk*128 + row): fragment ds_read_b128 hits 16 consecutive 16B slots -> 2-way
// bank alias only (free). ONE barrier per K-step: stage(next) issued before ds_read+MFMA of
// (cur), so the compiler's pre-barrier vmcnt(0) drain lands after a full compute phase.
// Bijective XCD-chunk swizzle (m204): same-m n-blocks share one XCD's L2 for the A panel.
// MODE 0: bf16 store, row-major ldc=kAttn (attn_enc projection).
// MODE 1: f32 scatter store for preds: row r -> (b=r&127, t=r>>7), out[(b*kT+t)*kVocab+col].
//         OOB W rows (col tile past Nv) read garbage inside workspace; never stored.
template <int MODE>
__global__ __launch_bounds__(256) void gemm128(
    const unsigned short* __restrict__ A, const unsigned short* __restrict__ W,
    const float* __restrict__ bias, unsigned short* __restrict__ Cb,
    float* __restrict__ Cf, int K, int Nv) {
  __shared__ unsigned short sA[2][128 * 32];   // 2 x 8 KB
  __shared__ unsigned short sB[2][128 * 32];   // 2 x 8 KB
  const int tid = threadIdx.x;
  const int lane = tid & 63, wave = tid >> 6;
  const int wm = wave >> 1, wn = wave & 1;
  const int q = lane >> 4, l = lane & 15;
  // bijective XCD-chunk swizzle (nwg need not be divisible by 8)
  const int nwg = gridDim.x * gridDim.y;
  const int orig = blockIdx.y * gridDim.x + blockIdx.x;
  const int qc = nwg >> 3, rc = nwg & 7;
  const int xcd = orig & 7, o8 = orig >> 3;
  const int wg = (xcd < rc ? xcd * (qc + 1) : rc * (qc + 1) + (xcd - rc) * qc) + o8;
  const int m0 = (wg / gridDim.x) * 128, n0 = (wg % gridDim.x) * 128;
  const int row0 = tid & 127, ch0 = tid >> 7;        // ch0 in {0,1}
  const long arow = (long)(m0 + row0) * K + ch0 * 8;
  const long brow = (long)(n0 + row0) * K + ch0 * 8;
  f32x4 acc[4][4] = {};

  auto stage = [&](int buf, int k0) {
    async16(A + arow + k0, &sA[buf][(ch0 * 128 + row0) * 8]);
    async16(A + arow + k0 + 16, &sA[buf][((ch0 + 2) * 128 + row0) * 8]);
    async16(W + brow + k0, &sB[buf][(ch0 * 128 + row0) * 8]);
    async16(W + brow + k0 + 16, &sB[buf][((ch0 + 2) * 128 + row0) * 8]);
  };

  stage(0, 0);
  __syncthreads();                 // compiler drains vmcnt before s_barrier
  int cur = 0;
  for (int k0 = 0; k0 < K; k0 += 32) {
    const bool last = (k0 + 32 >= K);
    if (!last) stage(cur ^ 1, k0 + 32);    // issue next-tile loads FIRST
    b16x8 af[4], bfr[4];
#pragma unroll
    for (int i = 0; i < 4; i++)
      af[i] = *(const b16x8*)&sA[cur][(q * 128 + wm * 64 + 16 * i + l) * 8];
#pragma unroll
    for (int j = 0; j < 4; j++)
      bfr[j] = *(const b16x8*)&sB[cur][(q * 128 + wn * 64 + 16 * j + l) * 8];
#pragma unroll
    for (int i = 0; i < 4; i++)
#pragma unroll
      for (int j = 0; j < 4; j++)
        acc[i][j] = __builtin_amdgcn_mfma_f32_16x16x32_bf16(af[i], bfr[j], acc[i][j], 0, 0, 0);
    if (!last) {
      __syncthreads();             // one barrier per K-step (drain covers this iter's stage)
      cur ^= 1;
    }
  }

#pragma unroll
  for (int i = 0; i < 4; i++) {
    const int row = m0 + wm * 64 + 16 * i + q * 4;
#pragma unroll
    for (int j = 0; j < 4; j++) {
      const int col = n0 + wn * 64 + 16 * j + l;
      if (col >= Nv) continue;
      const float bv = bias[col];
#pragma unroll
      for (int r = 0; r < 4; r++) {
        const float v = acc[i][j][r] + bv;
        if (MODE == 0) {
          Cb[(long)(row + r) * kAttn + col] = f2bf(v);
        } else {
          const int rr = row + r;
          Cf[((long)(rr & 127) * kT + (rr >> 7)) * (long)kVocab + col] = v;
        }
      }
    }
  }
}

// =========== generic small bf16 MFMA GEMM (64x64 tile, direct loads) — prelude/fallback ======
template <bool A_BF16, bool OUT_BF16>
__global__ __launch_bounds__(256) void gemm_bt(
    const void* __restrict__ A_, const unsigned short* __restrict__ W,
    const float* __restrict__ bias, float* __restrict__ C,
    unsigned short* __restrict__ Cb, int M, int N, int K, long ldc) {
  const int lane = threadIdx.x & 63;
  const int wave = threadIdx.x >> 6;
  const int wm = wave >> 1, wn = wave & 1;
  const int m0 = blockIdx.y * 64 + wm * 32;
  const int n0 = blockIdx.x * 64 + wn * 32;
  const int q = lane >> 4;
  const int l = lane & 15;
  f32x4 acc[2][2] = {};
  const unsigned short* Ab = (const unsigned short*)A_;
  const float* Af = (const float*)A_;

  for (int k0 = 0; k0 < K; k0 += 32) {
    const int ka = k0 + q * 8;
    b16x8 af[2], wf[2];
#pragma unroll
    for (int i = 0; i < 2; i++) {
      int r = m0 + 16 * i + l;
      if (r >= M) r = M - 1;
      if (A_BF16) {
        af[i] = *(const b16x8*)(Ab + (long)r * K + ka);
      } else {
        const float* p = Af + (long)r * K + ka;
        const f32x4 lo = *(const f32x4*)p;
        const f32x4 hi = *(const f32x4*)(p + 4);
        b16x8 t;
#pragma unroll
        for (int j = 0; j < 4; j++) {
          ((unsigned short*)&t)[j] = f2bf(lo[j]);
          ((unsigned short*)&t)[4 + j] = f2bf(hi[j]);
        }
        af[i] = t;
      }
    }
#pragma unroll
    for (int j = 0; j < 2; j++) {
      int r = n0 + 16 * j + l;
      if (r >= N) r = N - 1;
      wf[j] = *(const b16x8*)(W + (long)r * K + ka);
    }
#pragma unroll
    for (int i = 0; i < 2; i++)
#pragma unroll
      for (int j = 0; j < 2; j++)
        acc[i][j] = __builtin_amdgcn_mfma_f32_16x16x32_bf16(af[i], wf[j], acc[i][j], 0, 0, 0);
  }

#pragma unroll
  for (int i = 0; i < 2; i++)
#pragma unroll
    for (int j = 0; j < 2; j++) {
      const int col = n0 + 16 * j + l;
      if (col >= N) continue;
      const float bv = bias ? bias[col] : 0.0f;
#pragma unroll
      for (int r = 0; r < 4; r++) {
        const int row = m0 + 16 * i + q * 4 + r;
        if (row >= M) continue;
        const float v = acc[i][j][r] + bv;
        if (OUT_BF16) Cb[(long)row * ldc + col] = f2bf(v);
        else          C[(long)row * ldc + col] = v;
      }
    }
}

// =========== ad-only GEMM for t=0 (16 blocks): ad = h0@daw^T + dab ===========
__global__ __launch_bounds__(256) void adfc_kernel(
    const unsigned short* __restrict__ h_bf,
    const unsigned short* __restrict__ daw, const float* __restrict__ dab,
    float* __restrict__ ad_out) {
  const int blk = blockIdx.x;
  const int n0 = (blk & 7) * 64, m0 = (blk >> 3) * 64;
  const int lane = threadIdx.x & 63, wave = threadIdx.x >> 6;
  const int wm = wave >> 1, wn = wave & 1;
  const int q = lane >> 4, l = lane & 15;
  const int mi = m0 + wm * 32, ni = n0 + wn * 32;
  f32x4 acc[2][2] = {};

  for (int k0 = 0; k0 < 512; k0 += 64) {
    b16x8 af[2][2], wf[2][2];
#pragma unroll
    for (int u = 0; u < 2; u++) {
      const int ka = k0 + u * 32 + q * 8;
#pragma unroll
      for (int i = 0; i < 2; i++)
        af[u][i] = *(const b16x8*)(h_bf + (long)(mi + 16 * i + l) * 512 + ka);
#pragma unroll
      for (int j = 0; j < 2; j++)
        wf[u][j] = *(const b16x8*)(daw + (long)(ni + 16 * j + l) * 512 + ka);
    }
#pragma unroll
    for (int u = 0; u < 2; u++)
#pragma unroll
      for (int i = 0; i < 2; i++)
#pragma unroll
        for (int j = 0; j < 2; j++)
          acc[i][j] = __builtin_amdgcn_mfma_f32_16x16x32_bf16(af[u][i], wf[u][j], acc[i][j], 0, 0, 0);
  }
#pragma unroll
  for (int i = 0; i < 2; i++)
#pragma unroll
    for (int j = 0; j < 2; j++) {
      const int col = ni + 16 * j + l;
      const float bv = dab[col];
#pragma unroll
      for (int r = 0; r < 4; r++) {
        const int row = mi + 16 * i + q * 4 + r;
        ad_out[(long)row * 512 + col] = acc[i][j][r] + bv;
      }
    }
}

// =========== attention: energy + softmax + context (ad precomputed) ===========
// grid (kB, 2): each half covers 1024 context dims; context p-split x2 in-block.
template <bool SRC_BF16>
__global__ __launch_bounds__(256) void attn2(
    const void* __restrict__ enc_, const unsigned short* __restrict__ attn_enc_bf,
    const float* __restrict__ ad_g, const float* __restrict__ faw,
    const float* __restrict__ fab, float* __restrict__ alphas,
    unsigned short* __restrict__ ctx, int t) {
  const int b = blockIdx.x;
  const int half = blockIdx.y;
  const int tid = threadIdx.x;
  const int lane = tid & 63, wave = tid >> 6;
  __shared__ float ad_s[512];
  __shared__ float e_sm[kP];
  __shared__ float red[4];
  __shared__ float cred[128][8];

  ad_s[tid] = ad_g[b * kAttn + tid];
  ad_s[tid + 256] = ad_g[b * kAttn + tid + 256];
  __syncthreads();

  // energy[p] = fw . relu(attn_enc[b,p,:] + ad) + fb  — wave per p, lane-split-8
  float ad8[8], w8[8];
  const int a0 = lane * 8;
#pragma unroll
  for (int j = 0; j < 8; j++) { ad8[j] = ad_s[a0 + j]; w8[j] = faw[a0 + j]; }
  const float fb0 = fab[0];
  for (int p = wave; p < kP; p += 4) {
    const b16x8 rv = *(const b16x8*)(attn_enc_bf + ((long)(b * kP + p)) * kAttn + a0);
    float s = 0.f;
#pragma unroll
    for (int j = 0; j < 8; j++)
      s += w8[j] * fmaxf(bf2f(((const unsigned short*)&rv)[j]) + ad8[j], 0.f);
#pragma unroll
    for (int off = 32; off > 0; off >>= 1) s += __shfl_down(s, off, 64);
    if (lane == 0) e_sm[p] = s + fb0;
  }
  __syncthreads();

  // softmax over 196
  const float v = (tid < kP) ? e_sm[tid] : -3.0e38f;
  float m = v;
#pragma unroll
  for (int off = 32; off > 0; off >>= 1) m = fmaxf(m, __shfl_down(m, off, 64));
  if (lane == 0) red[wave] = m;
  __syncthreads();
  m = fmaxf(fmaxf(red[0], red[1]), fmaxf(red[2], red[3]));
  const float ex = (tid < kP) ? expf(v - m) : 0.f;
  float s = ex;
#pragma unroll
  for (int off = 32; off > 0; off >>= 1) s += __shfl_down(s, off, 64);
  if (lane == 0) red[wave] = s;
  __syncthreads();
  s = red[0] + red[1] + red[2] + red[3];
  __syncthreads();
  const float alpha = ex / s;
  if (tid < kP) {
    e_sm[tid] = alpha;
    if (half == 0) alphas[((long)b * kT + t) * kP + tid] = alpha;
  }
  __syncthreads();

  // context: this half covers dims [half*1024, half*1024+1024); 8 dims/thread, p-split x2
  const int pg = tid >> 7, th = tid & 127;
  const int e = half * 1024 + th * 8;
  float a8[8] = {};
  if (SRC_BF16) {
    const unsigned short* base = (const unsigned short*)enc_ + (long)b * kP * kEnc + e;
    const int pbeg = pg * 98;
#pragma unroll 2
    for (int p = pbeg; p < pbeg + 98; p++) {
      const float a = e_sm[p];
      const b16x8 rv = *(const b16x8*)(base + (long)p * kEnc);
#pragma unroll
      for (int j = 0; j < 8; j++) a8[j] += a * bf2f(((const unsigned short*)&rv)[j]);
    }
  } else {
    const float* base = (const float*)enc_ + (long)b * kP * kEnc + e;
    const int pbeg = pg * 98;
#pragma unroll 2
    for (int p = pbeg; p < pbeg + 98; p++) {
      const float a = e_sm[p];
      const f32x4 lo = *(const f32x4*)(base + (long)p * kEnc);
      const f32x4 hi = *(const f32x4*)(base + (long)p * kEnc + 4);
#pragma unroll
      for (int j = 0; j < 4; j++) { a8[j] += a * lo[j]; a8[4 + j] += a * hi[j]; }
    }
  }
  if (pg == 1) {
#pragma unroll
    for (int j = 0; j < 8; j++) cred[th][j] = a8[j];
  }
  __syncthreads();
  if (pg == 0) {
    u16x4 o0, o1;
#pragma unroll
    for (int j = 0; j < 4; j++) {
      o0[j] = f2bf(a8[j] + cred[th][j]);
      o1[j] = f2bf(a8[4 + j] + cred[th][4 + j]);
    }
    *(u16x4*)(ctx + (long)b * kEnc + e) = o0;
    *(u16x4*)(ctx + (long)b * kEnc + e + 4) = o1;
  }
}

// =========== gates GEMM, split-K x4 ===========
__global__ __launch_bounds__(256) void gemm_gates(
    const unsigned short* __restrict__ embs_t, const unsigned short* __restrict__ ctx,
    const unsigned short* __restrict__ hbf, const unsigned short* __restrict__ Wih,
    const unsigned short* __restrict__ Whh, float* __restrict__ gates_part) {
  const int lane = threadIdx.x & 63;
  const int wave = threadIdx.x >> 6;
  const int wm = wave >> 1, wn = wave & 1;
  const int m0 = blockIdx.y * 64 + wm * 32;   // M=128
  const int n0 = blockIdx.x * 64 + wn * 32;   // N=2048
  const int z = blockIdx.z;                    // k-chunk of 768
  const int q = lane >> 4;
  const int l = lane & 15;
  f32x4 acc[2][2] = {};
  float* gout = gates_part + (long)z * kB * 2048;

  const int kbeg = z * 768, kend = kbeg + 768;
  for (int k0 = kbeg; k0 < kend; k0 += 32) {
    b16x8 af[2], wf[2];
#pragma unroll
    for (int i = 0; i < 2; i++) {
      const int r = m0 + 16 * i + l;
      const unsigned short* p;
      if (k0 < 512)        p = embs_t + (long)r * kEmb + k0;
      else if (k0 < 2560)  p = ctx + (long)r * kEnc + (k0 - 512);
      else                 p = hbf + (long)r * kDec + (k0 - 2560);
      af[i] = *(const b16x8*)(p + q * 8);
    }
#pragma unroll
    for (int j = 0; j < 2; j++) {
      const int r = n0 + 16 * j + l;
      const unsigned short* p;
      if (k0 < 2560) p = Wih + (long)r * 2560 + k0;
      else           p = Whh + (long)r * 512 + (k0 - 2560);
      wf[j] = *(const b16x8*)(p + q * 8);
    }
#pragma unroll
    for (int i = 0; i < 2; i++)
#pragma unroll
      for (int j = 0; j < 2; j++)
        acc[i][j] = __builtin_amdgcn_mfma_f32_16x16x32_bf16(af[i], wf[j], acc[i][j], 0, 0, 0);
  }
#pragma unroll
  for (int i = 0; i < 2; i++)
#pragma unroll
    for (int j = 0; j < 2; j++) {
      const int col = n0 + 16 * j + l;
#pragma unroll
      for (int r = 0; r < 4; r++) {
        const int row = m0 + 16 * i + q * 4 + r;
        gout[(long)row * 2048 + col] = acc[i][j][r];
      }
    }
}

// =========== fused LSTM pointwise + ad-matvec ===========
// 1 block per batch row b. Phase 1: combine 4 split-K gate partials + bias, update c,
// write h_{t+1} (bf16) to h_hist slot AND to LDS. Phase 2: ad[b,:] = h@daw^T + dab
// (each thread: two 512-long dots; daw is L2-resident, h broadcast from LDS).
__global__ __launch_bounds__(256) void lstm_ad(
    const float* __restrict__ gp, const float* __restrict__ bsum,
    float* __restrict__ c, unsigned short* __restrict__ h_out,
    const unsigned short* __restrict__ daw, const float* __restrict__ dab,
    float* __restrict__ ad_out) {
  const int b = blockIdx.x;
  const int tid = threadIdx.x;
  __shared__ unsigned short h_s[512];

#pragma unroll
  for (int u = 0; u < 2; u++) {
    const int d = tid + u * 256;
    float g4[4];
#pragma unroll
    for (int g = 0; g < 4; g++) {
      const int col = g * 512 + d;
      float s = bsum[col];
#pragma unroll
      for (int z = 0; z < 4; z++) s += gp[(long)z * kB * 2048 + (long)b * 2048 + col];
      g4[g] = s;
    }
    const float si = 1.f / (1.f + expf(-g4[0]));
    const float sf = 1.f / (1.f + expf(-g4[1]));
    const float so = 1.f / (1.f + expf(-g4[3]));
    const long idx = (long)b * 512 + d;
    const float cn = sf * c[idx] + si * tanhf(g4[2]);
    const float hn = so * tanhf(cn);
    c[idx] = cn;
    const unsigned short hb = f2bf(hn);
    h_out[idx] = hb;
    h_s[d] = hb;
  }
  __syncthreads();

#pragma unroll
  for (int u = 0; u < 2; u++) {
    const int r = tid + u * 256;
    const unsigned short* wr = daw + (long)r * 512;
    float s = 0.f;
    for (int k = 0; k < 512; k += 8) {
      const b16x8 hv = *(const b16x8*)&h_s[k];          // broadcast read
      const b16x8 wv = *(const b16x8*)(wr + k);
#pragma unroll
      for (int j = 0; j < 8; j++)
        s += bf2f(((const unsigned short*)&hv)[j]) * bf2f(((const unsigned short*)&wv)[j]);
    }
    ad_out[(long)b * 512 + r] = s + dab[r];
  }
}

// =========== prelude kernels ===========
template <bool SRC_BF16>
__global__ __launch_bounds__(256) void mean_kernel(
    const void* __restrict__ enc_, unsigned short* __restrict__ mean_bf) {
  const int b = blockIdx.x;
  const int e = threadIdx.x * 8;
  float acc[8] = {};
  if (SRC_BF16) {
    const unsigned short* base = (const unsigned short*)enc_ + (long)b * kP * kEnc + e;
    for (int p = 0; p < kP; p++) {
      const b16x8 v = *(const b16x8*)(base + (long)p * kEnc);
#pragma unroll
      for (int j = 0; j < 8; j++) acc[j] += bf2f(((const unsigned short*)&v)[j]);
    }
  } else {
    const float* base = (const float*)enc_ + (long)b * kP * kEnc + e;
    for (int p = 0; p < kP; p++) {
      const f32x4 lo = *(const f32x4*)(base + (long)p * kEnc);
      const f32x4 hi = *(const f32x4*)(base + (long)p * kEnc + 4);
#pragma unroll
      for (int j = 0; j < 4; j++) { acc[j] += lo[j]; acc[4 + j] += hi[j]; }
    }
  }
#pragma unroll
  for (int j = 0; j < 8; j++)
    mean_bf[(long)b * kEnc + e + j] = f2bf(acc[j] * (1.0f / 196.0f));
}

__global__ __launch_bounds__(256) void f32_to_bf16_vec(
    const float* __restrict__ src, unsigned short* __restrict__ dst, long n4) {
  for (long i = blockIdx.x * (long)blockDim.x + threadIdx.x; i < n4;
       i += (long)gridDim.x * blockDim.x) {
    const f32x4 v = *(const f32x4*)(src + i * 4);
    u16x4 o;
#pragma unroll
    for (int j = 0; j < 4; j++) o[j] = f2bf(v[j]);
    *(u16x4*)(dst + i * 4) = o;
  }
}

__global__ __launch_bounds__(256) void gather_emb(
    const float* __restrict__ embedding, const int* __restrict__ captions,
    unsigned short* __restrict__ embs) {
  const int r = blockIdx.x;           // t*128 + b
  const int t = r >> 7, b = r & 127;
  const int cap = captions[b * kT + t];
  const float* src = embedding + (long)cap * kEmb;
  unsigned short* dst = embs + (long)r * kEmb;
  for (int i = threadIdx.x; i < kEmb; i += 256) dst[i] = f2bf(src[i]);
}

__global__ void bias_sum_k(const float* __restrict__ b1, const float* __restrict__ b2,
                           float* __restrict__ o) {
  const int i = blockIdx.x * 256 + threadIdx.x;
  if (i < 2048) o[i] = b1[i] + b2[i];
}

// ---------------- host ----------------
extern "C" void kernel_launch(void* const* d_in, const int* in_sizes, int n_in,
                              void* d_out, int out_size, void* d_ws, size_t ws_size,
                              hipStream_t stream) {
  const float* enc = (const float*)d_in[0];
  const int* captions = (const int*)d_in[1];
  const float* embedding = (const float*)d_in[3];
  const float* eaw = (const float*)d_in[4];
  const float* eab = (const float*)d_in[5];
  const float* daw = (const float*)d_in[6];
  const float* dab = (const float*)d_in[7];
  const float* faw = (const float*)d_in[8];
  const float* fab = (const float*)d_in[9];
  const float* Wih = (const float*)d_in[10];
  const float* bih = (const float*)d_in[11];
  const float* Whh = (const float*)d_in[12];
  const float* bhh = (const float*)d_in[13];
  const float* ihw = (const float*)d_in[14];
  const float* ihb = (const float*)d_in[15];
  const float* icw = (const float*)d_in[16];
  const float* icb = (const float*)d_in[17];
  const float* fcw = (const float*)d_in[18];
  const float* fcb = (const float*)d_in[19];

  float* out = (float*)d_out;                        // outputs [B,T,VOCAB]
  float* alphas = out + (long)kB * kT * kVocab;      // alphas  [B,T,P]

  char* ws = (char*)d_ws;
  size_t off = 0;
  auto alloc = [&](size_t bytes) -> void* {
    void* p = ws + off;
    off = (off + bytes + 255) & ~(size_t)255;
    return p;
  };
  unsigned short* attn_enc_bf = (unsigned short*)alloc((size_t)kB * kP * kAttn * 2);
  unsigned short* Wih_bf = (unsigned short*)alloc((size_t)2048 * 2560 * 2);
  unsigned short* Whh_bf = (unsigned short*)alloc((size_t)2048 * 512 * 2);
  unsigned short* fcw_bf = (unsigned short*)alloc((size_t)kVocab * kDec * 2);
  unsigned short* eaw_bf = (unsigned short*)alloc((size_t)kAttn * kEnc * 2);
  unsigned short* daw_bf = (unsigned short*)alloc((size_t)kAttn * kDec * 2);
  unsigned short* ihw_bf = (unsigned short*)alloc((size_t)kDec * kEnc * 2);
  unsigned short* icw_bf = (unsigned short*)alloc((size_t)kDec * kEnc * 2);
  unsigned short* embs_bf = (unsigned short*)alloc((size_t)kT * kB * kEmb * 2);
  unsigned short* mean_bf = (unsigned short*)alloc((size_t)kB * kEnc * 2);
  float* h = (float*)alloc((size_t)kB * kDec * 4);
  float* c = (float*)alloc((size_t)kB * kDec * 4);
  // h history: slot 0 = init h; slot t+1 = h after lstm step t (bf16). preds_t uses slot t+1.
  unsigned short* h_hist = (unsigned short*)alloc((size_t)(kT + 1) * kB * kDec * 2);
  float* ad_buf = (float*)alloc((size_t)kB * kAttn * 4);
  unsigned short* ctx_bf = (unsigned short*)alloc((size_t)kB * kEnc * 2);
  float* gates_part = (float*)alloc((size_t)4 * kB * 2048 * 4);
  float* bsum = (float*)alloc((size_t)2048 * 4);
  unsigned short* enc_bf = (unsigned short*)alloc((size_t)kB * kP * kEnc * 2);
  const bool have_enc_bf = (off <= ws_size);

  auto cvt = [&](const float* s, unsigned short* d, long n) {
    const long n4 = n / 4;
    long g = (n4 + 255) / 256;
    if (g > 2048) g = 2048;
    f32_to_bf16_vec<<<dim3((unsigned)g), dim3(256), 0, stream>>>(s, d, n4);
  };

  // ---- prelude
  cvt(eaw, eaw_bf, (long)kAttn * kEnc);
  cvt(daw, daw_bf, (long)kAttn * kDec);
  cvt(Wih, Wih_bf, (long)2048 * 2560);
  cvt(Whh, Whh_bf, (long)2048 * 512);
  cvt(fcw, fcw_bf, (long)kVocab * kDec);
  cvt(ihw, ihw_bf, (long)kDec * kEnc);
  cvt(icw, icw_bf, (long)kDec * kEnc);
  if (have_enc_bf) cvt(enc, enc_bf, (long)kB * kP * kEnc);
  bias_sum_k<<<8, 256, 0, stream>>>(bih, bhh, bsum);
  gather_emb<<<kT * kB, 256, 0, stream>>>(embedding, captions, embs_bf);
  if (have_enc_bf)
    mean_kernel<true><<<kB, 256, 0, stream>>>(enc_bf, mean_bf);
  else
    mean_kernel<false><<<kB, 256, 0, stream>>>(enc, mean_bf);

  gemm_bt<true, false><<<dim3(kDec / 64, kB / 64), 256, 0, stream>>>(
      mean_bf, ihw_bf, ihb, h, (unsigned short*)nullptr, kB, kDec, kEnc, kDec);
  gemm_bt<true, false><<<dim3(kDec / 64, kB / 64), 256, 0, stream>>>(
      mean_bf, icw_bf, icb, c, (unsigned short*)nullptr, kB, kDec, kEnc, kDec);
  cvt(h, h_hist, (long)kB * kDec);   // slot 0 = h_0

  // attn_enc projection: [25088,2048] @ [512,2048]^T -> bf16 [25088,512]
  if (have_enc_bf)
    gemm128<0><<<dim3(kAttn / 128, (kB * kP) / 128), 256, 0, stream>>>(
        enc_bf, eaw_bf, eab, attn_enc_bf, (float*)nullptr, kEnc, kAttn);
  else
    gemm_bt<false, true><<<dim3(kAttn / 64, (kB * kP) / 64), 256, 0, stream>>>(
        enc, eaw_bf, eab, (float*)nullptr, attn_enc_bf, kB * kP, kAttn, kEnc, kAttn);

  // ad for t=0 (h_0)
  adfc_kernel<<<16, 256, 0, stream>>>(h_hist, daw_bf, dab, ad_buf);

  // ---- T sequential decode steps: attn -> gates -> fused lstm+ad (3 kernels/step)
  for (int t = 0; t < kT; t++) {
    const unsigned short* hcur = h_hist + (long)t * kB * kDec;

    if (have_enc_bf)
      attn2<true><<<dim3(kB, 2), 256, 0, stream>>>(
          enc_bf, attn_enc_bf, ad_buf, faw, fab, alphas, ctx_bf, t);
    else
      attn2<false><<<dim3(kB, 2), 256, 0, stream>>>(
          enc, attn_enc_bf, ad_buf, faw, fab, alphas, ctx_bf, t);

    gemm_gates<<<dim3(2048 / 64, kB / 64, 4), 256, 0, stream>>>(
        embs_bf + (long)t * kB * kEmb, ctx_bf, hcur, Wih_bf, Whh_bf, gates_part);

    lstm_ad<<<kB, 256, 0, stream>>>(
        gates_part, bsum, c, h_hist + (long)(t + 1) * kB * kDec, daw_bf, dab, ad_buf);
  }

  // batched preds: [kT*kB, VOCAB] = h_hist[1..20] @ fcw^T + fcb, scattered to out[b,t,:]
  gemm128<1><<<dim3((kVocab + 127) / 128, kT * kB / 128), 256, 0, stream>>>(
      h_hist + (long)kB * kDec, fcw_bf, fcb, (unsigned short*)nullptr, out, kDec, kVocab);
}

// Round 3
// 2124.882 us; speedup vs baseline: 1.1133x; 1.1133x over previous
//
#include <hip/hip_runtime.h>

// ---------------- problem constants ----------------
constexpr int kB = 128, kP = 196, kT = 20;
constexpr int kVocab = 10000, kEnc = 2048, kEmb = 512, kDec = 512, kAttn = 512;

typedef __bf16 b16x8 __attribute__((ext_vector_type(8)));
typedef __bf16 b16x4 __attribute__((ext_vector_type(4)));
typedef float f32x4 __attribute__((ext_vector_type(4)));
typedef unsigned short u16x4 __attribute__((ext_vector_type(4)));

__device__ __forceinline__ unsigned short f2bf(float f) {
  unsigned int u = __float_as_uint(f);
  u += 0x7fffu + ((u >> 16) & 1u);          // RNE (inputs finite)
  return (unsigned short)(u >> 16);
}
__device__ __forceinline__ float bf2f(unsigned short h) {
  return __uint_as_float(((unsigned int)h) << 16);
}

__device__ __forceinline__ void async16(const void* g, void* l) {
  __builtin_amdgcn_global_load_lds(
      (const __attribute__((address_space(1))) unsigned int*)g,
      (__attribute__((address_space(3))) unsigned int*)l, 16, 0, 0);
}

// =========== 128x128-tile bf16 GEMM, BK=64 double-buffered: C = A[M,K]@W[N,K]^T + bias =======
// 4 waves (2x2), 4x4 acc/wave. A AND B staged via global_load_lds, chunk-major LDS
// (slot = chunk*128 + row, chunk 0..7): fragment ds_read_b128 hits 16 consecutive 16B slots
// -> 2-way bank alias only (free). T3 2-phase: stage(next) issued before ds_read+MFMA of
// (cur); the pre-barrier vmcnt(0) drain lands after 32 MFMA/wave of compute.
// Bijective XCD-chunk swizzle (m204).
// MODE 0: bf16 store, row-major ldc=kAttn (attn_enc projection).
// MODE 1: f32 scatter store for preds: row r -> (b=r&127, t=r>>7), out[(b*kT+t)*kVocab+col].
//         OOB W rows (col tile past Nv) read garbage inside workspace; never stored.
template <int MODE>
__global__ __launch_bounds__(256) void gemm128(
    const unsigned short* __restrict__ A, const unsigned short* __restrict__ W,
    const float* __restrict__ bias, unsigned short* __restrict__ Cb,
    float* __restrict__ Cf, int K, int Nv) {
  __shared__ unsigned short sA[2][128 * 64];   // 2 x 16 KB
  __shared__ unsigned short sB[2][128 * 64];   // 2 x 16 KB
  const int tid = threadIdx.x;
  const int lane = tid & 63, wave = tid >> 6;
  const int wm = wave >> 1, wn = wave & 1;
  const int q = lane >> 4, l = lane & 15;
  // bijective XCD-chunk swizzle (nwg need not be divisible by 8)
  const int nwg = gridDim.x * gridDim.y;
  const int orig = blockIdx.y * gridDim.x + blockIdx.x;
  const int qc = nwg >> 3, rc = nwg & 7;
  const int xcd = orig & 7, o8 = orig >> 3;
  const int wg = (xcd < rc ? xcd * (qc + 1) : rc * (qc + 1) + (xcd - rc) * qc) + o8;
  const int m0 = (wg / gridDim.x) * 128, n0 = (wg % gridDim.x) * 128;
  const int row0 = tid & 127, ch0 = tid >> 7;        // ch0 in {0,1}
  const long arow = (long)(m0 + row0) * K;
  const long brow = (long)(n0 + row0) * K;
  f32x4 acc[4][4] = {};

  auto stage = [&](int buf, int k0) {
#pragma unroll
    for (int cc = 0; cc < 4; cc++) {
      const int ch = ch0 + cc * 2;               // covers chunks 0..7
      async16(A + arow + k0 + ch * 8, &sA[buf][(ch * 128 + row0) * 8]);
      async16(W + brow + k0 + ch * 8, &sB[buf][(ch * 128 + row0) * 8]);
    }
  };

  stage(0, 0);
  __syncthreads();                 // compiler drains vmcnt before s_barrier
  int cur = 0;
  for (int k0 = 0; k0 < K; k0 += 64) {
    const bool last = (k0 + 64 >= K);
    if (!last) stage(cur ^ 1, k0 + 64);    // issue next-tile loads FIRST
    b16x8 af[2][4], bfr[2][4];
#pragma unroll
    for (int u = 0; u < 2; u++) {
      const int cb = u * 4 + q;
#pragma unroll
      for (int i = 0; i < 4; i++)
        af[u][i] = *(const b16x8*)&sA[cur][(cb * 128 + wm * 64 + 16 * i + l) * 8];
#pragma unroll
      for (int j = 0; j < 4; j++)
        bfr[u][j] = *(const b16x8*)&sB[cur][(cb * 128 + wn * 64 + 16 * j + l) * 8];
    }
#pragma unroll
    for (int u = 0; u < 2; u++)
#pragma unroll
      for (int i = 0; i < 4; i++)
#pragma unroll
        for (int j = 0; j < 4; j++)
          acc[i][j] = __builtin_amdgcn_mfma_f32_16x16x32_bf16(af[u][i], bfr[u][j], acc[i][j], 0, 0, 0);
    if (!last) {
      __syncthreads();             // one barrier per K-step (drain covers this iter's stage)
      cur ^= 1;
    }
  }

#pragma unroll
  for (int i = 0; i < 4; i++) {
    const int row = m0 + wm * 64 + 16 * i + q * 4;
#pragma unroll
    for (int j = 0; j < 4; j++) {
      const int col = n0 + wn * 64 + 16 * j + l;
      if (col >= Nv) continue;
      const float bv = bias[col];
#pragma unroll
      for (int r = 0; r < 4; r++) {
        const float v = acc[i][j][r] + bv;
        if (MODE == 0) {
          Cb[(long)(row + r) * kAttn + col] = f2bf(v);
        } else {
          const int rr = row + r;
          Cf[((long)(rr & 127) * kT + (rr >> 7)) * (long)kVocab + col] = v;
        }
      }
    }
  }
}

// =========== generic small bf16 MFMA GEMM (64x64 tile, direct loads) — prelude/fallback ======
template <bool A_BF16, bool OUT_BF16>
__global__ __launch_bounds__(256) void gemm_bt(
    const void* __restrict__ A_, const unsigned short* __restrict__ W,
    const float* __restrict__ bias, float* __restrict__ C,
    unsigned short* __restrict__ Cb, int M, int N, int K, long ldc) {
  const int lane = threadIdx.x & 63;
  const int wave = threadIdx.x >> 6;
  const int wm = wave >> 1, wn = wave & 1;
  const int m0 = blockIdx.y * 64 + wm * 32;
  const int n0 = blockIdx.x * 64 + wn * 32;
  const int q = lane >> 4;
  const int l = lane & 15;
  f32x4 acc[2][2] = {};
  const unsigned short* Ab = (const unsigned short*)A_;
  const float* Af = (const float*)A_;

  for (int k0 = 0; k0 < K; k0 += 32) {
    const int ka = k0 + q * 8;
    b16x8 af[2], wf[2];
#pragma unroll
    for (int i = 0; i < 2; i++) {
      int r = m0 + 16 * i + l;
      if (r >= M) r = M - 1;
      if (A_BF16) {
        af[i] = *(const b16x8*)(Ab + (long)r * K + ka);
      } else {
        const float* p = Af + (long)r * K + ka;
        const f32x4 lo = *(const f32x4*)p;
        const f32x4 hi = *(const f32x4*)(p + 4);
        b16x8 t;
#pragma unroll
        for (int j = 0; j < 4; j++) {
          ((unsigned short*)&t)[j] = f2bf(lo[j]);
          ((unsigned short*)&t)[4 + j] = f2bf(hi[j]);
        }
        af[i] = t;
      }
    }
#pragma unroll
    for (int j = 0; j < 2; j++) {
      int r = n0 + 16 * j + l;
      if (r >= N) r = N - 1;
      wf[j] = *(const b16x8*)(W + (long)r * K + ka);
    }
#pragma unroll
    for (int i = 0; i < 2; i++)
#pragma unroll
      for (int j = 0; j < 2; j++)
        acc[i][j] = __builtin_amdgcn_mfma_f32_16x16x32_bf16(af[i], wf[j], acc[i][j], 0, 0, 0);
  }

#pragma unroll
  for (int i = 0; i < 2; i++)
#pragma unroll
    for (int j = 0; j < 2; j++) {
      const int col = n0 + 16 * j + l;
      if (col >= N) continue;
      const float bv = bias ? bias[col] : 0.0f;
#pragma unroll
      for (int r = 0; r < 4; r++) {
        const int row = m0 + 16 * i + q * 4 + r;
        if (row >= M) continue;
        const float v = acc[i][j][r] + bv;
        if (OUT_BF16) Cb[(long)row * ldc + col] = f2bf(v);
        else          C[(long)row * ldc + col] = v;
      }
    }
}

// =========== ad-only GEMM for t=0 (16 blocks): ad = h0@daw^T + dab ===========
__global__ __launch_bounds__(256) void adfc_kernel(
    const unsigned short* __restrict__ h_bf,
    const unsigned short* __restrict__ daw, const float* __restrict__ dab,
    float* __restrict__ ad_out) {
  const int blk = blockIdx.x;
  const int n0 = (blk & 7) * 64, m0 = (blk >> 3) * 64;
  const int lane = threadIdx.x & 63, wave = threadIdx.x >> 6;
  const int wm = wave >> 1, wn = wave & 1;
  const int q = lane >> 4, l = lane & 15;
  const int mi = m0 + wm * 32, ni = n0 + wn * 32;
  f32x4 acc[2][2] = {};

  for (int k0 = 0; k0 < 512; k0 += 64) {
    b16x8 af[2][2], wf[2][2];
#pragma unroll
    for (int u = 0; u < 2; u++) {
      const int ka = k0 + u * 32 + q * 8;
#pragma unroll
      for (int i = 0; i < 2; i++)
        af[u][i] = *(const b16x8*)(h_bf + (long)(mi + 16 * i + l) * 512 + ka);
#pragma unroll
      for (int j = 0; j < 2; j++)
        wf[u][j] = *(const b16x8*)(daw + (long)(ni + 16 * j + l) * 512 + ka);
    }
#pragma unroll
    for (int u = 0; u < 2; u++)
#pragma unroll
      for (int i = 0; i < 2; i++)
#pragma unroll
        for (int j = 0; j < 2; j++)
          acc[i][j] = __builtin_amdgcn_mfma_f32_16x16x32_bf16(af[u][i], wf[u][j], acc[i][j], 0, 0, 0);
  }
#pragma unroll
  for (int i = 0; i < 2; i++)
#pragma unroll
    for (int j = 0; j < 2; j++) {
      const int col = ni + 16 * j + l;
      const float bv = dab[col];
#pragma unroll
      for (int r = 0; r < 4; r++) {
        const int row = mi + 16 * i + q * 4 + r;
        ad_out[(long)row * 512 + col] = acc[i][j][r] + bv;
      }
    }
}

// =========== attention: energy + softmax + context (ad precomputed) ===========
// grid (kB, 2): each half covers 1024 context dims; context p-split x2 in-block.
// Energy: unroll x4 (4 row loads in flight). Context: unroll x8 (8 loads in flight).
template <bool SRC_BF16>
__global__ __launch_bounds__(256) void attn2(
    const void* __restrict__ enc_, const unsigned short* __restrict__ attn_enc_bf,
    const float* __restrict__ ad_g, const float* __restrict__ faw,
    const float* __restrict__ fab, float* __restrict__ alphas,
    unsigned short* __restrict__ ctx, int t) {
  const int b = blockIdx.x;
  const int half = blockIdx.y;
  const int tid = threadIdx.x;
  const int lane = tid & 63, wave = tid >> 6;
  __shared__ float ad_s[512];
  __shared__ float e_sm[kP];
  __shared__ float red[4];
  __shared__ float cred[128][8];

  ad_s[tid] = ad_g[b * kAttn + tid];
  ad_s[tid + 256] = ad_g[b * kAttn + tid + 256];
  __syncthreads();

  // energy[p] = fw . relu(attn_enc[b,p,:] + ad) + fb  — wave per p, lane-split-8
  float ad8[8], w8[8];
  const int a0 = lane * 8;
#pragma unroll
  for (int j = 0; j < 8; j++) { ad8[j] = ad_s[a0 + j]; w8[j] = faw[a0 + j]; }
  const float fb0 = fab[0];
  {
    int p = wave;
#pragma unroll 1
    for (int it = 0; it < 12; it++, p += 16) {
      b16x8 rv[4];
#pragma unroll
      for (int u = 0; u < 4; u++)
        rv[u] = *(const b16x8*)(attn_enc_bf + ((long)(b * kP + p + 4 * u)) * kAttn + a0);
      float s4[4];
#pragma unroll
      for (int u = 0; u < 4; u++) {
        float s = 0.f;
#pragma unroll
        for (int j = 0; j < 8; j++)
          s += w8[j] * fmaxf(bf2f(((const unsigned short*)&rv[u])[j]) + ad8[j], 0.f);
        s4[u] = s;
      }
#pragma unroll
      for (int u = 0; u < 4; u++) {
        float s = s4[u];
#pragma unroll
        for (int off = 32; off > 0; off >>= 1) s += __shfl_down(s, off, 64);
        if (lane == 0) e_sm[p + 4 * u] = s + fb0;
      }
    }
    // tail: p = wave + 192 (<196)
    {
      const b16x8 rv = *(const b16x8*)(attn_enc_bf + ((long)(b * kP + p)) * kAttn + a0);
      float s = 0.f;
#pragma unroll
      for (int j = 0; j < 8; j++)
        s += w8[j] * fmaxf(bf2f(((const unsigned short*)&rv)[j]) + ad8[j], 0.f);
#pragma unroll
      for (int off = 32; off > 0; off >>= 1) s += __shfl_down(s, off, 64);
      if (lane == 0) e_sm[p] = s + fb0;
    }
  }
  __syncthreads();

  // softmax over 196
  const float v = (tid < kP) ? e_sm[tid] : -3.0e38f;
  float m = v;
#pragma unroll
  for (int off = 32; off > 0; off >>= 1) m = fmaxf(m, __shfl_down(m, off, 64));
  if (lane == 0) red[wave] = m;
  __syncthreads();
  m = fmaxf(fmaxf(red[0], red[1]), fmaxf(red[2], red[3]));
  const float ex = (tid < kP) ? expf(v - m) : 0.f;
  float s = ex;
#pragma unroll
  for (int off = 32; off > 0; off >>= 1) s += __shfl_down(s, off, 64);
  if (lane == 0) red[wave] = s;
  __syncthreads();
  s = red[0] + red[1] + red[2] + red[3];
  __syncthreads();
  const float alpha = ex / s;
  if (tid < kP) {
    e_sm[tid] = alpha;
    if (half == 0) alphas[((long)b * kT + t) * kP + tid] = alpha;
  }
  __syncthreads();

  // context: this half covers dims [half*1024, half*1024+1024); 8 dims/thread, p-split x2
  const int pg = tid >> 7, th = tid & 127;
  const int e = half * 1024 + th * 8;
  float a8[8] = {};
  if (SRC_BF16) {
    const unsigned short* base = (const unsigned short*)enc_ + (long)b * kP * kEnc + e;
    int p = pg * 98;
#pragma unroll 1
    for (int it = 0; it < 12; it++, p += 8) {     // 96 of 98
      b16x8 rv[8];
#pragma unroll
      for (int u = 0; u < 8; u++) rv[u] = *(const b16x8*)(base + (long)(p + u) * kEnc);
#pragma unroll
      for (int u = 0; u < 8; u++) {
        const float a = e_sm[p + u];
#pragma unroll
        for (int j = 0; j < 8; j++) a8[j] += a * bf2f(((const unsigned short*)&rv[u])[j]);
      }
    }
#pragma unroll
    for (int u = 0; u < 2; u++, p++) {            // tail 2
      const float a = e_sm[p];
      const b16x8 rv = *(const b16x8*)(base + (long)p * kEnc);
#pragma unroll
      for (int j = 0; j < 8; j++) a8[j] += a * bf2f(((const unsigned short*)&rv)[j]);
    }
  } else {
    const float* base = (const float*)enc_ + (long)b * kP * kEnc + e;
    const int pbeg = pg * 98;
#pragma unroll 2
    for (int p = pbeg; p < pbeg + 98; p++) {
      const float a = e_sm[p];
      const f32x4 lo = *(const f32x4*)(base + (long)p * kEnc);
      const f32x4 hi = *(const f32x4*)(base + (long)p * kEnc + 4);
#pragma unroll
      for (int j = 0; j < 4; j++) { a8[j] += a * lo[j]; a8[4 + j] += a * hi[j]; }
    }
  }
  if (pg == 1) {
#pragma unroll
    for (int j = 0; j < 8; j++) cred[th][j] = a8[j];
  }
  __syncthreads();
  if (pg == 0) {
    u16x4 o0, o1;
#pragma unroll
    for (int j = 0; j < 4; j++) {
      o0[j] = f2bf(a8[j] + cred[th][j]);
      o1[j] = f2bf(a8[4 + j] + cred[th][4 + j]);
    }
    *(u16x4*)(ctx + (long)b * kEnc + e) = o0;
    *(u16x4*)(ctx + (long)b * kEnc + e + 4) = o1;
  }
}

// =========== gates GEMM, split-K x4, BK=64 inner (8 loads in flight) ===========
__global__ __launch_bounds__(256) void gemm_gates(
    const unsigned short* __restrict__ embs_t, const unsigned short* __restrict__ ctx,
    const unsigned short* __restrict__ hbf, const unsigned short* __restrict__ Wih,
    const unsigned short* __restrict__ Whh, float* __restrict__ gates_part) {
  const int lane = threadIdx.x & 63;
  const int wave = threadIdx.x >> 6;
  const int wm = wave >> 1, wn = wave & 1;
  const int m0 = blockIdx.y * 64 + wm * 32;   // M=128
  const int n0 = blockIdx.x * 64 + wn * 32;   // N=2048
  const int z = blockIdx.z;                    // k-chunk of 768
  const int q = lane >> 4;
  const int l = lane & 15;
  f32x4 acc[2][2] = {};
  float* gout = gates_part + (long)z * kB * 2048;

  const int kbeg = z * 768, kend = kbeg + 768;
  for (int k0 = kbeg; k0 < kend; k0 += 64) {
    b16x8 af[2][2], wf[2][2];
#pragma unroll
    for (int u = 0; u < 2; u++) {
      const int k = k0 + u * 32;               // region boundaries (512, 2560) are x64-aligned
#pragma unroll
      for (int i = 0; i < 2; i++) {
        const int r = m0 + 16 * i + l;
        const unsigned short* p;
        if (k < 512)        p = embs_t + (long)r * kEmb + k;
        else if (k < 2560)  p = ctx + (long)r * kEnc + (k - 512);
        else                p = hbf + (long)r * kDec + (k - 2560);
        af[u][i] = *(const b16x8*)(p + q * 8);
      }
#pragma unroll
      for (int j = 0; j < 2; j++) {
        const int r = n0 + 16 * j + l;
        const unsigned short* p;
        if (k < 2560) p = Wih + (long)r * 2560 + k;
        else          p = Whh + (long)r * 512 + (k - 2560);
        wf[u][j] = *(const b16x8*)(p + q * 8);
      }
    }
#pragma unroll
    for (int u = 0; u < 2; u++)
#pragma unroll
      for (int i = 0; i < 2; i++)
#pragma unroll
        for (int j = 0; j < 2; j++)
          acc[i][j] = __builtin_amdgcn_mfma_f32_16x16x32_bf16(af[u][i], wf[u][j], acc[i][j], 0, 0, 0);
  }
#pragma unroll
  for (int i = 0; i < 2; i++)
#pragma unroll
    for (int j = 0; j < 2; j++) {
      const int col = n0 + 16 * j + l;
#pragma unroll
      for (int r = 0; r < 4; r++) {
        const int row = m0 + 16 * i + q * 4 + r;
        gout[(long)row * 2048 + col] = acc[i][j][r];
      }
    }
}

// =========== fused LSTM pointwise + ad-matvec ===========
// 1 block per batch row b. Phase 1: combine 4 split-K gate partials + bias, update c,
// write h_{t+1} (bf16) to h_hist slot AND (bf16-rounded, f32) to LDS. Phase 2:
// ad[b,:] = h@daw^T + dab — each thread two 512-dots, 4-way split accumulators.
__global__ __launch_bounds__(256) void lstm_ad(
    const float* __restrict__ gp, const float* __restrict__ bsum,
    float* __restrict__ c, unsigned short* __restrict__ h_out,
    const unsigned short* __restrict__ daw, const float* __restrict__ dab,
    float* __restrict__ ad_out) {
  const int b = blockIdx.x;
  const int tid = threadIdx.x;
  __shared__ float h_s[512];

#pragma unroll
  for (int u = 0; u < 2; u++) {
    const int d = tid + u * 256;
    float g4[4];
#pragma unroll
    for (int g = 0; g < 4; g++) {
      const int col = g * 512 + d;
      float s = bsum[col];
#pragma unroll
      for (int z = 0; z < 4; z++) s += gp[(long)z * kB * 2048 + (long)b * 2048 + col];
      g4[g] = s;
    }
    const float si = 1.f / (1.f + expf(-g4[0]));
    const float sf = 1.f / (1.f + expf(-g4[1]));
    const float so = 1.f / (1.f + expf(-g4[3]));
    const long idx = (long)b * 512 + d;
    const float cn = sf * c[idx] + si * tanhf(g4[2]);
    const float hn = so * tanhf(cn);
    c[idx] = cn;
    const unsigned short hb = f2bf(hn);
    h_out[idx] = hb;
    h_s[d] = bf2f(hb);              // bf16-rounded value (numerics match bf16-h path)
  }
  __syncthreads();

#pragma unroll
  for (int u = 0; u < 2; u++) {
    const int r = tid + u * 256;
    const unsigned short* wr = daw + (long)r * 512;
    float s0 = 0.f, s1 = 0.f, s2 = 0.f, s3 = 0.f;
#pragma unroll 1
    for (int k = 0; k < 512; k += 32) {
      b16x8 wv[4];
#pragma unroll
      for (int v = 0; v < 4; v++) wv[v] = *(const b16x8*)(wr + k + v * 8);
#pragma unroll
      for (int j = 0; j < 8; j++) s0 += h_s[k + j]      * bf2f(((const unsigned short*)&wv[0])[j]);
#pragma unroll
      for (int j = 0; j < 8; j++) s1 += h_s[k + 8 + j]  * bf2f(((const unsigned short*)&wv[1])[j]);
#pragma unroll
      for (int j = 0; j < 8; j++) s2 += h_s[k + 16 + j] * bf2f(((const unsigned short*)&wv[2])[j]);
#pragma unroll
      for (int j = 0; j < 8; j++) s3 += h_s[k + 24 + j] * bf2f(((const unsigned short*)&wv[3])[j]);
    }
    ad_out[(long)b * 512 + r] = ((s0 + s1) + (s2 + s3)) + dab[r];
  }
}

// =========== prelude kernels ===========
// Fused: read enc f32 once -> write enc_bf AND per-b mean (bf16). grid (kB, 2), 4 dims/thread.
__global__ __launch_bounds__(256) void mean_cvt(
    const float* __restrict__ enc, unsigned short* __restrict__ enc_bf,
    unsigned short* __restrict__ mean_bf) {
  const int b = blockIdx.x;
  const int e = blockIdx.y * 1024 + threadIdx.x * 4;
  const float* base = enc + (long)b * kP * kEnc + e;
  unsigned short* ob = enc_bf + (long)b * kP * kEnc + e;
  f32x4 acc = {};
  int p = 0;
#pragma unroll 1
  for (int it = 0; it < 49; it++, p += 4) {
    f32x4 v[4];
#pragma unroll
    for (int u = 0; u < 4; u++) v[u] = *(const f32x4*)(base + (long)(p + u) * kEnc);
#pragma unroll
    for (int u = 0; u < 4; u++) {
      u16x4 o;
#pragma unroll
      for (int j = 0; j < 4; j++) { acc[j] += v[u][j]; o[j] = f2bf(v[u][j]); }
      *(u16x4*)(ob + (long)(p + u) * kEnc) = o;
    }
  }
  u16x4 om;
#pragma unroll
  for (int j = 0; j < 4; j++) om[j] = f2bf(acc[j] * (1.0f / 196.0f));
  *(u16x4*)(mean_bf + (long)b * kEnc + e) = om;
}

template <bool SRC_BF16>
__global__ __launch_bounds__(256) void mean_kernel(
    const void* __restrict__ enc_, unsigned short* __restrict__ mean_bf) {
  const int b = blockIdx.x;
  const int e = threadIdx.x * 8;
  float acc[8] = {};
  if (SRC_BF16) {
    const unsigned short* base = (const unsigned short*)enc_ + (long)b * kP * kEnc + e;
    for (int p = 0; p < kP; p++) {
      const b16x8 v = *(const b16x8*)(base + (long)p * kEnc);
#pragma unroll
      for (int j = 0; j < 8; j++) acc[j] += bf2f(((const unsigned short*)&v)[j]);
    }
  } else {
    const float* base = (const float*)enc_ + (long)b * kP * kEnc + e;
    for (int p = 0; p < kP; p++) {
      const f32x4 lo = *(const f32x4*)(base + (long)p * kEnc);
      const f32x4 hi = *(const f32x4*)(base + (long)p * kEnc + 4);
#pragma unroll
      for (int j = 0; j < 4; j++) { acc[j] += lo[j]; acc[4 + j] += hi[j]; }
    }
  }
#pragma unroll
  for (int j = 0; j < 8; j++)
    mean_bf[(long)b * kEnc + e + j] = f2bf(acc[j] * (1.0f / 196.0f));
}

__global__ __launch_bounds__(256) void f32_to_bf16_vec(
    const float* __restrict__ src, unsigned short* __restrict__ dst, long n4) {
  for (long i = blockIdx.x * (long)blockDim.x + threadIdx.x; i < n4;
       i += (long)gridDim.x * blockDim.x) {
    const f32x4 v = *(const f32x4*)(src + i * 4);
    u16x4 o;
#pragma unroll
    for (int j = 0; j < 4; j++) o[j] = f2bf(v[j]);
    *(u16x4*)(dst + i * 4) = o;
  }
}

__global__ __launch_bounds__(256) void gather_emb(
    const float* __restrict__ embedding, const int* __restrict__ captions,
    unsigned short* __restrict__ embs) {
  const int r = blockIdx.x;           // t*128 + b
  const int t = r >> 7, b = r & 127;
  const int cap = captions[b * kT + t];
  const float* src = embedding + (long)cap * kEmb;
  unsigned short* dst = embs + (long)r * kEmb;
  for (int i = threadIdx.x; i < kEmb; i += 256) dst[i] = f2bf(src[i]);
}

__global__ void bias_sum_k(const float* __restrict__ b1, const float* __restrict__ b2,
                           float* __restrict__ o) {
  const int i = blockIdx.x * 256 + threadIdx.x;
  if (i < 2048) o[i] = b1[i] + b2[i];
}

// ---------------- host ----------------
extern "C" void kernel_launch(void* const* d_in, const int* in_sizes, int n_in,
                              void* d_out, int out_size, void* d_ws, size_t ws_size,
                              hipStream_t stream) {
  const float* enc = (const float*)d_in[0];
  const int* captions = (const int*)d_in[1];
  const float* embedding = (const float*)d_in[3];
  const float* eaw = (const float*)d_in[4];
  const float* eab = (const float*)d_in[5];
  const float* daw = (const float*)d_in[6];
  const float* dab = (const float*)d_in[7];
  const float* faw = (const float*)d_in[8];
  const float* fab = (const float*)d_in[9];
  const float* Wih = (const float*)d_in[10];
  const float* bih = (const float*)d_in[11];
  const float* Whh = (const float*)d_in[12];
  const float* bhh = (const float*)d_in[13];
  const float* ihw = (const float*)d_in[14];
  const float* ihb = (const float*)d_in[15];
  const float* icw = (const float*)d_in[16];
  const float* icb = (const float*)d_in[17];
  const float* fcw = (const float*)d_in[18];
  const float* fcb = (const float*)d_in[19];

  float* out = (float*)d_out;                        // outputs [B,T,VOCAB]
  float* alphas = out + (long)kB * kT * kVocab;      // alphas  [B,T,P]

  char* ws = (char*)d_ws;
  size_t off = 0;
  auto alloc = [&](size_t bytes) -> void* {
    void* p = ws + off;
    off = (off + bytes + 255) & ~(size_t)255;
    return p;
  };
  unsigned short* attn_enc_bf = (unsigned short*)alloc((size_t)kB * kP * kAttn * 2);
  unsigned short* Wih_bf = (unsigned short*)alloc((size_t)2048 * 2560 * 2);
  unsigned short* Whh_bf = (unsigned short*)alloc((size_t)2048 * 512 * 2);
  unsigned short* fcw_bf = (unsigned short*)alloc((size_t)kVocab * kDec * 2);
  unsigned short* eaw_bf = (unsigned short*)alloc((size_t)kAttn * kEnc * 2);
  unsigned short* daw_bf = (unsigned short*)alloc((size_t)kAttn * kDec * 2);
  unsigned short* ihw_bf = (unsigned short*)alloc((size_t)kDec * kEnc * 2);
  unsigned short* icw_bf = (unsigned short*)alloc((size_t)kDec * kEnc * 2);
  unsigned short* embs_bf = (unsigned short*)alloc((size_t)kT * kB * kEmb * 2);
  unsigned short* mean_bf = (unsigned short*)alloc((size_t)kB * kEnc * 2);
  float* c = (float*)alloc((size_t)kB * kDec * 4);
  // h history: slot 0 = init h; slot t+1 = h after lstm step t (bf16). preds_t uses slot t+1.
  unsigned short* h_hist = (unsigned short*)alloc((size_t)(kT + 1) * kB * kDec * 2);
  float* ad_buf = (float*)alloc((size_t)kB * kAttn * 4);
  unsigned short* ctx_bf = (unsigned short*)alloc((size_t)kB * kEnc * 2);
  float* gates_part = (float*)alloc((size_t)4 * kB * 2048 * 4);
  float* bsum = (float*)alloc((size_t)2048 * 4);
  unsigned short* enc_bf = (unsigned short*)alloc((size_t)kB * kP * kEnc * 2);
  const bool have_enc_bf = (off <= ws_size);

  auto cvt = [&](const float* s, unsigned short* d, long n) {
    const long n4 = n / 4;
    long g = (n4 + 255) / 256;
    if (g > 2048) g = 2048;
    f32_to_bf16_vec<<<dim3((unsigned)g), dim3(256), 0, stream>>>(s, d, n4);
  };

  // ---- prelude
  cvt(eaw, eaw_bf, (long)kAttn * kEnc);
  cvt(daw, daw_bf, (long)kAttn * kDec);
  cvt(Wih, Wih_bf, (long)2048 * 2560);
  cvt(Whh, Whh_bf, (long)2048 * 512);
  cvt(fcw, fcw_bf, (long)kVocab * kDec);
  cvt(ihw, ihw_bf, (long)kDec * kEnc);
  cvt(icw, icw_bf, (long)kDec * kEnc);
  bias_sum_k<<<8, 256, 0, stream>>>(bih, bhh, bsum);
  gather_emb<<<kT * kB, 256, 0, stream>>>(embedding, captions, embs_bf);
  if (have_enc_bf)
    mean_cvt<<<dim3(kB, 2), 256, 0, stream>>>(enc, enc_bf, mean_bf);  // fused cvt + mean
  else
    mean_kernel<false><<<kB, 256, 0, stream>>>(enc, mean_bf);

  // h0 (bf16 direct into h_hist slot 0) and c0
  gemm_bt<true, true><<<dim3(kDec / 64, kB / 64), 256, 0, stream>>>(
      mean_bf, ihw_bf, ihb, (float*)nullptr, h_hist, kB, kDec, kEnc, kDec);
  gemm_bt<true, false><<<dim3(kDec / 64, kB / 64), 256, 0, stream>>>(
      mean_bf, icw_bf, icb, c, (unsigned short*)nullptr, kB, kDec, kEnc, kDec);

  // attn_enc projection: [25088,2048] @ [512,2048]^T -> bf16 [25088,512]
  if (have_enc_bf)
    gemm128<0><<<dim3(kAttn / 128, (kB * kP) / 128), 256, 0, stream>>>(
        enc_bf, eaw_bf, eab, attn_enc_bf, (float*)nullptr, kEnc, kAttn);
  else
    gemm_bt<false, true><<<dim3(kAttn / 64, (kB * kP) / 64), 256, 0, stream>>>(
        enc, eaw_bf, eab, (float*)nullptr, attn_enc_bf, kB * kP, kAttn, kEnc, kAttn);

  // ad for t=0 (h_0)
  adfc_kernel<<<16, 256, 0, stream>>>(h_hist, daw_bf, dab, ad_buf);

  // ---- T sequential decode steps: attn -> gates -> fused lstm+ad (3 kernels/step)
  for (int t = 0; t < kT; t++) {
    const unsigned short* hcur = h_hist + (long)t * kB * kDec;

    if (have_enc_bf)
      attn2<true><<<dim3(kB, 2), 256, 0, stream>>>(
          enc_bf, attn_enc_bf, ad_buf, faw, fab, alphas, ctx_bf, t);
    else
      attn2<false><<<dim3(kB, 2), 256, 0, stream>>>(
          enc, attn_enc_bf, ad_buf, faw, fab, alphas, ctx_bf, t);

    gemm_gates<<<dim3(2048 / 64, kB / 64, 4), 256, 0, stream>>>(
        embs_bf + (long)t * kB * kEmb, ctx_bf, hcur, Wih_bf, Whh_bf, gates_part);

    lstm_ad<<<kB, 256, 0, stream>>>(
        gates_part, bsum, c, h_hist + (long)(t + 1) * kB * kDec, daw_bf, dab, ad_buf);
  }

  // batched preds: [kT*kB, VOCAB] = h_hist[1..20] @ fcw^T + fcb, scattered to out[b,t,:]
  gemm128<1><<<dim3((kVocab + 127) / 128, kT * kB / 128), 256, 0, stream>>>(
      h_hist + (long)kB * kDec, fcw_bf, fcb, (unsigned short*)nullptr, out, kDec, kVocab);
}

// Round 4
// 2052.109 us; speedup vs baseline: 1.1528x; 1.0355x over previous
//
#include <hip/hip_runtime.h>

// ---------------- problem constants ----------------
constexpr int kB = 128, kP = 196, kT = 20;
constexpr int kVocab = 10000, kEnc = 2048, kEmb = 512, kDec = 512, kAttn = 512;

typedef __bf16 b16x8 __attribute__((ext_vector_type(8)));
typedef __bf16 b16x4 __attribute__((ext_vector_type(4)));
typedef float f32x4 __attribute__((ext_vector_type(4)));
typedef unsigned short u16x4 __attribute__((ext_vector_type(4)));

__device__ __forceinline__ unsigned short f2bf(float f) {
  unsigned int u = __float_as_uint(f);
  u += 0x7fffu + ((u >> 16) & 1u);          // RNE (inputs finite)
  return (unsigned short)(u >> 16);
}
__device__ __forceinline__ float bf2f(unsigned short h) {
  return __uint_as_float(((unsigned int)h) << 16);
}

__device__ __forceinline__ void async16(const void* g, void* l) {
  __builtin_amdgcn_global_load_lds(
      (const __attribute__((address_space(1))) unsigned int*)g,
      (__attribute__((address_space(3))) unsigned int*)l, 16, 0, 0);
}

// =========== 128x128-tile bf16 GEMM, counted-vmcnt 2-buffer pipeline (T3+T4+T5) ===========
// C = A[M,K]@W[N,K]^T + bias. 4 waves (2x2), 4x4 acc/wave, BK=32, LDS 32 KB.
// Chunk-major LDS (slot = chunk*128 + row): ds_read_b128 fragments hit 16 consecutive
// 16B slots -> 2-way bank alias only (free; measured 0 conflicts).
// Pipeline: stage(t) = 4 global_load_lds/thread. Prologue stages tiles 0,1. Each iter:
//   s_waitcnt vmcnt(4)  (tile t landed; tile t+1's 4 loads stay IN FLIGHT - never drain to 0)
//   s_barrier ; ds_read+MFMA(buf t&1) ; s_barrier ; stage(tile t+2 into buf t&1)
// Raw barriers (no __syncthreads) so the compiler cannot insert a vmcnt(0) drain.
// Bijective XCD-chunk swizzle (m204).
// MODE 0: bf16 store, row-major ldc=kAttn (attn_enc projection).
// MODE 1: f32 scatter store for preds: row r -> (b=r&127, t=r>>7), out[(b*kT+t)*kVocab+col].
//         OOB W rows (col tile past Nv) read garbage inside workspace; never stored.
template <int MODE>
__global__ __launch_bounds__(256) void gemm128(
    const unsigned short* __restrict__ A, const unsigned short* __restrict__ W,
    const float* __restrict__ bias, unsigned short* __restrict__ Cb,
    float* __restrict__ Cf, int K, int Nv) {
  __shared__ unsigned short sA[2][128 * 32];   // 2 x 8 KB
  __shared__ unsigned short sB[2][128 * 32];   // 2 x 8 KB
  const int tid = threadIdx.x;
  const int lane = tid & 63, wave = tid >> 6;
  const int wm = wave >> 1, wn = wave & 1;
  const int q = lane >> 4, l = lane & 15;
  // bijective XCD-chunk swizzle (nwg need not be divisible by 8)
  const int nwg = gridDim.x * gridDim.y;
  const int orig = blockIdx.y * gridDim.x + blockIdx.x;
  const int qc = nwg >> 3, rc = nwg & 7;
  const int xcd = orig & 7, o8 = orig >> 3;
  const int wg = (xcd < rc ? xcd * (qc + 1) : rc * (qc + 1) + (xcd - rc) * qc) + o8;
  const int m0 = (wg / gridDim.x) * 128, n0 = (wg % gridDim.x) * 128;
  const int row0 = tid & 127, ch0 = tid >> 7;        // ch0 in {0,1}
  const long arow = (long)(m0 + row0) * K + ch0 * 8;
  const long brow = (long)(n0 + row0) * K + ch0 * 8;
  f32x4 acc[4][4] = {};

  auto stage = [&](int buf, int k0) {
    async16(A + arow + k0, &sA[buf][(ch0 * 128 + row0) * 8]);
    async16(A + arow + k0 + 16, &sA[buf][((ch0 + 2) * 128 + row0) * 8]);
    async16(W + brow + k0, &sB[buf][(ch0 * 128 + row0) * 8]);
    async16(W + brow + k0 + 16, &sB[buf][((ch0 + 2) * 128 + row0) * 8]);
  };

  const int nt = K >> 5;
  stage(0, 0);
  stage(1, 32);

  for (int t = 0; t < nt; ++t) {
    const int cur = t & 1;
    if (t + 1 < nt) {
      asm volatile("s_waitcnt vmcnt(4)" ::: "memory");   // tile t landed; t+1 in flight
    } else {
      asm volatile("s_waitcnt vmcnt(0)" ::: "memory");   // last tile: drain
    }
    __builtin_amdgcn_sched_barrier(0);
    __builtin_amdgcn_s_barrier();                         // all waves' tile-t loads landed
    __builtin_amdgcn_sched_barrier(0);

    b16x8 af[4], bfr[4];
#pragma unroll
    for (int i = 0; i < 4; i++)
      af[i] = *(const b16x8*)&sA[cur][(q * 128 + wm * 64 + 16 * i + l) * 8];
#pragma unroll
    for (int j = 0; j < 4; j++)
      bfr[j] = *(const b16x8*)&sB[cur][(q * 128 + wn * 64 + 16 * j + l) * 8];
    __builtin_amdgcn_s_setprio(1);
#pragma unroll
    for (int i = 0; i < 4; i++)
#pragma unroll
      for (int j = 0; j < 4; j++)
        acc[i][j] = __builtin_amdgcn_mfma_f32_16x16x32_bf16(af[i], bfr[j], acc[i][j], 0, 0, 0);
    __builtin_amdgcn_s_setprio(0);

    __builtin_amdgcn_sched_barrier(0);
    __builtin_amdgcn_s_barrier();                         // all waves done reading buf cur
    __builtin_amdgcn_sched_barrier(0);
    if (t + 2 < nt) stage(cur, (t + 2) * 32);             // reuse buf for tile t+2
  }

#pragma unroll
  for (int i = 0; i < 4; i++) {
    const int row = m0 + wm * 64 + 16 * i + q * 4;
#pragma unroll
    for (int j = 0; j < 4; j++) {
      const int col = n0 + wn * 64 + 16 * j + l;
      if (col >= Nv) continue;
      const float bv = bias[col];
#pragma unroll
      for (int r = 0; r < 4; r++) {
        const float v = acc[i][j][r] + bv;
        if (MODE == 0) {
          Cb[(long)(row + r) * kAttn + col] = f2bf(v);
        } else {
          const int rr = row + r;
          Cf[((long)(rr & 127) * kT + (rr >> 7)) * (long)kVocab + col] = v;
        }
      }
    }
  }
}

// =========== generic small bf16 MFMA GEMM (64x64 tile, direct loads) — prelude/fallback ======
template <bool A_BF16, bool OUT_BF16>
__global__ __launch_bounds__(256) void gemm_bt(
    const void* __restrict__ A_, const unsigned short* __restrict__ W,
    const float* __restrict__ bias, float* __restrict__ C,
    unsigned short* __restrict__ Cb, int M, int N, int K, long ldc) {
  const int lane = threadIdx.x & 63;
  const int wave = threadIdx.x >> 6;
  const int wm = wave >> 1, wn = wave & 1;
  const int m0 = blockIdx.y * 64 + wm * 32;
  const int n0 = blockIdx.x * 64 + wn * 32;
  const int q = lane >> 4;
  const int l = lane & 15;
  f32x4 acc[2][2] = {};
  const unsigned short* Ab = (const unsigned short*)A_;
  const float* Af = (const float*)A_;

  for (int k0 = 0; k0 < K; k0 += 32) {
    const int ka = k0 + q * 8;
    b16x8 af[2], wf[2];
#pragma unroll
    for (int i = 0; i < 2; i++) {
      int r = m0 + 16 * i + l;
      if (r >= M) r = M - 1;
      if (A_BF16) {
        af[i] = *(const b16x8*)(Ab + (long)r * K + ka);
      } else {
        const float* p = Af + (long)r * K + ka;
        const f32x4 lo = *(const f32x4*)p;
        const f32x4 hi = *(const f32x4*)(p + 4);
        b16x8 t;
#pragma unroll
        for (int j = 0; j < 4; j++) {
          ((unsigned short*)&t)[j] = f2bf(lo[j]);
          ((unsigned short*)&t)[4 + j] = f2bf(hi[j]);
        }
        af[i] = t;
      }
    }
#pragma unroll
    for (int j = 0; j < 2; j++) {
      int r = n0 + 16 * j + l;
      if (r >= N) r = N - 1;
      wf[j] = *(const b16x8*)(W + (long)r * K + ka);
    }
#pragma unroll
    for (int i = 0; i < 2; i++)
#pragma unroll
      for (int j = 0; j < 2; j++)
        acc[i][j] = __builtin_amdgcn_mfma_f32_16x16x32_bf16(af[i], wf[j], acc[i][j], 0, 0, 0);
  }

#pragma unroll
  for (int i = 0; i < 2; i++)
#pragma unroll
    for (int j = 0; j < 2; j++) {
      const int col = n0 + 16 * j + l;
      if (col >= N) continue;
      const float bv = bias ? bias[col] : 0.0f;
#pragma unroll
      for (int r = 0; r < 4; r++) {
        const int row = m0 + 16 * i + q * 4 + r;
        if (row >= M) continue;
        const float v = acc[i][j][r] + bv;
        if (OUT_BF16) Cb[(long)row * ldc + col] = f2bf(v);
        else          C[(long)row * ldc + col] = v;
      }
    }
}

// =========== ad-only GEMM for t=0 (16 blocks): ad = h0@daw^T + dab ===========
__global__ __launch_bounds__(256) void adfc_kernel(
    const unsigned short* __restrict__ h_bf,
    const unsigned short* __restrict__ daw, const float* __restrict__ dab,
    float* __restrict__ ad_out) {
  const int blk = blockIdx.x;
  const int n0 = (blk & 7) * 64, m0 = (blk >> 3) * 64;
  const int lane = threadIdx.x & 63, wave = threadIdx.x >> 6;
  const int wm = wave >> 1, wn = wave & 1;
  const int q = lane >> 4, l = lane & 15;
  const int mi = m0 + wm * 32, ni = n0 + wn * 32;
  f32x4 acc[2][2] = {};

  for (int k0 = 0; k0 < 512; k0 += 64) {
    b16x8 af[2][2], wf[2][2];
#pragma unroll
    for (int u = 0; u < 2; u++) {
      const int ka = k0 + u * 32 + q * 8;
#pragma unroll
      for (int i = 0; i < 2; i++)
        af[u][i] = *(const b16x8*)(h_bf + (long)(mi + 16 * i + l) * 512 + ka);
#pragma unroll
      for (int j = 0; j < 2; j++)
        wf[u][j] = *(const b16x8*)(daw + (long)(ni + 16 * j + l) * 512 + ka);
    }
#pragma unroll
    for (int u = 0; u < 2; u++)
#pragma unroll
      for (int i = 0; i < 2; i++)
#pragma unroll
        for (int j = 0; j < 2; j++)
          acc[i][j] = __builtin_amdgcn_mfma_f32_16x16x32_bf16(af[u][i], wf[u][j], acc[i][j], 0, 0, 0);
  }
#pragma unroll
  for (int i = 0; i < 2; i++)
#pragma unroll
    for (int j = 0; j < 2; j++) {
      const int col = ni + 16 * j + l;
      const float bv = dab[col];
#pragma unroll
      for (int r = 0; r < 4; r++) {
        const int row = mi + 16 * i + q * 4 + r;
        ad_out[(long)row * 512 + col] = acc[i][j][r] + bv;
      }
    }
}

// =========== attention: energy + softmax + context (ad precomputed) ===========
// grid (kB, 2): each half covers 1024 context dims; context p-split x2 in-block.
// Energy: unroll x4 (4 row loads in flight). Context: unroll x8 (8 loads in flight).
template <bool SRC_BF16>
__global__ __launch_bounds__(256) void attn2(
    const void* __restrict__ enc_, const unsigned short* __restrict__ attn_enc_bf,
    const float* __restrict__ ad_g, const float* __restrict__ faw,
    const float* __restrict__ fab, float* __restrict__ alphas,
    unsigned short* __restrict__ ctx, int t) {
  const int b = blockIdx.x;
  const int half = blockIdx.y;
  const int tid = threadIdx.x;
  const int lane = tid & 63, wave = tid >> 6;
  __shared__ float ad_s[512];
  __shared__ float e_sm[kP];
  __shared__ float red[4];
  __shared__ float cred[128][8];

  ad_s[tid] = ad_g[b * kAttn + tid];
  ad_s[tid + 256] = ad_g[b * kAttn + tid + 256];
  __syncthreads();

  // energy[p] = fw . relu(attn_enc[b,p,:] + ad) + fb  — wave per p, lane-split-8
  float ad8[8], w8[8];
  const int a0 = lane * 8;
#pragma unroll
  for (int j = 0; j < 8; j++) { ad8[j] = ad_s[a0 + j]; w8[j] = faw[a0 + j]; }
  const float fb0 = fab[0];
  {
    int p = wave;
#pragma unroll 1
    for (int it = 0; it < 12; it++, p += 16) {
      b16x8 rv[4];
#pragma unroll
      for (int u = 0; u < 4; u++)
        rv[u] = *(const b16x8*)(attn_enc_bf + ((long)(b * kP + p + 4 * u)) * kAttn + a0);
      float s4[4];
#pragma unroll
      for (int u = 0; u < 4; u++) {
        float s = 0.f;
#pragma unroll
        for (int j = 0; j < 8; j++)
          s += w8[j] * fmaxf(bf2f(((const unsigned short*)&rv[u])[j]) + ad8[j], 0.f);
        s4[u] = s;
      }
#pragma unroll
      for (int u = 0; u < 4; u++) {
        float s = s4[u];
#pragma unroll
        for (int off = 32; off > 0; off >>= 1) s += __shfl_down(s, off, 64);
        if (lane == 0) e_sm[p + 4 * u] = s + fb0;
      }
    }
    // tail: p = wave + 192 (<196)
    {
      const b16x8 rv = *(const b16x8*)(attn_enc_bf + ((long)(b * kP + p)) * kAttn + a0);
      float s = 0.f;
#pragma unroll
      for (int j = 0; j < 8; j++)
        s += w8[j] * fmaxf(bf2f(((const unsigned short*)&rv)[j]) + ad8[j], 0.f);
#pragma unroll
      for (int off = 32; off > 0; off >>= 1) s += __shfl_down(s, off, 64);
      if (lane == 0) e_sm[p] = s + fb0;
    }
  }
  __syncthreads();

  // softmax over 196
  const float v = (tid < kP) ? e_sm[tid] : -3.0e38f;
  float m = v;
#pragma unroll
  for (int off = 32; off > 0; off >>= 1) m = fmaxf(m, __shfl_down(m, off, 64));
  if (lane == 0) red[wave] = m;
  __syncthreads();
  m = fmaxf(fmaxf(red[0], red[1]), fmaxf(red[2], red[3]));
  const float ex = (tid < kP) ? expf(v - m) : 0.f;
  float s = ex;
#pragma unroll
  for (int off = 32; off > 0; off >>= 1) s += __shfl_down(s, off, 64);
  if (lane == 0) red[wave] = s;
  __syncthreads();
  s = red[0] + red[1] + red[2] + red[3];
  __syncthreads();
  const float alpha = ex / s;
  if (tid < kP) {
    e_sm[tid] = alpha;
    if (half == 0) alphas[((long)b * kT + t) * kP + tid] = alpha;
  }
  __syncthreads();

  // context: this half covers dims [half*1024, half*1024+1024); 8 dims/thread, p-split x2
  const int pg = tid >> 7, th = tid & 127;
  const int e = half * 1024 + th * 8;
  float a8[8] = {};
  if (SRC_BF16) {
    const unsigned short* base = (const unsigned short*)enc_ + (long)b * kP * kEnc + e;
    int p = pg * 98;
#pragma unroll 1
    for (int it = 0; it < 12; it++, p += 8) {     // 96 of 98
      b16x8 rv[8];
#pragma unroll
      for (int u = 0; u < 8; u++) rv[u] = *(const b16x8*)(base + (long)(p + u) * kEnc);
#pragma unroll
      for (int u = 0; u < 8; u++) {
        const float a = e_sm[p + u];
#pragma unroll
        for (int j = 0; j < 8; j++) a8[j] += a * bf2f(((const unsigned short*)&rv[u])[j]);
      }
    }
#pragma unroll
    for (int u = 0; u < 2; u++, p++) {            // tail 2
      const float a = e_sm[p];
      const b16x8 rv = *(const b16x8*)(base + (long)p * kEnc);
#pragma unroll
      for (int j = 0; j < 8; j++) a8[j] += a * bf2f(((const unsigned short*)&rv)[j]);
    }
  } else {
    const float* base = (const float*)enc_ + (long)b * kP * kEnc + e;
    const int pbeg = pg * 98;
#pragma unroll 2
    for (int p = pbeg; p < pbeg + 98; p++) {
      const float a = e_sm[p];
      const f32x4 lo = *(const f32x4*)(base + (long)p * kEnc);
      const f32x4 hi = *(const f32x4*)(base + (long)p * kEnc + 4);
#pragma unroll
      for (int j = 0; j < 4; j++) { a8[j] += a * lo[j]; a8[4 + j] += a * hi[j]; }
    }
  }
  if (pg == 1) {
#pragma unroll
    for (int j = 0; j < 8; j++) cred[th][j] = a8[j];
  }
  __syncthreads();
  if (pg == 0) {
    u16x4 o0, o1;
#pragma unroll
    for (int j = 0; j < 4; j++) {
      o0[j] = f2bf(a8[j] + cred[th][j]);
      o1[j] = f2bf(a8[4 + j] + cred[th][4 + j]);
    }
    *(u16x4*)(ctx + (long)b * kEnc + e) = o0;
    *(u16x4*)(ctx + (long)b * kEnc + e + 4) = o1;
  }
}

// =========== gates GEMM, split-K x4, register double-buffered K-loop ===========
#define GATES_LOADK(pp, kk)                                                          \
  {                                                                                  \
    _Pragma("unroll")                                                                \
    for (int u = 0; u < 2; u++) {                                                    \
      const int k = (kk) + u * 32;                                                   \
      _Pragma("unroll")                                                              \
      for (int i = 0; i < 2; i++) {                                                  \
        const int r = m0 + 16 * i + l;                                               \
        const unsigned short* p;                                                     \
        if (k < 512)        p = embs_t + (long)r * kEmb + k;                         \
        else if (k < 2560)  p = ctx + (long)r * kEnc + (k - 512);                    \
        else                p = hbf + (long)r * kDec + (k - 2560);                   \
        af[pp][u][i] = *(const b16x8*)(p + q * 8);                                   \
      }                                                                              \
      _Pragma("unroll")                                                              \
      for (int j = 0; j < 2; j++) {                                                  \
        const int r = n0 + 16 * j + l;                                               \
        const unsigned short* p;                                                     \
        if (k < 2560) p = Wih + (long)r * 2560 + k;                                  \
        else          p = Whh + (long)r * 512 + (k - 2560);                          \
        wf[pp][u][j] = *(const b16x8*)(p + q * 8);                                   \
      }                                                                              \
    }                                                                                \
  }

__global__ __launch_bounds__(256) void gemm_gates(
    const unsigned short* __restrict__ embs_t, const unsigned short* __restrict__ ctx,
    const unsigned short* __restrict__ hbf, const unsigned short* __restrict__ Wih,
    const unsigned short* __restrict__ Whh, float* __restrict__ gates_part) {
  const int lane = threadIdx.x & 63;
  const int wave = threadIdx.x >> 6;
  const int wm = wave >> 1, wn = wave & 1;
  const int m0 = blockIdx.y * 64 + wm * 32;   // M=128
  const int n0 = blockIdx.x * 64 + wn * 32;   // N=2048
  const int z = blockIdx.z;                    // k-chunk of 768
  const int q = lane >> 4;
  const int l = lane & 15;
  f32x4 acc[2][2] = {};
  float* gout = gates_part + (long)z * kB * 2048;

  const int kbeg = z * 768;
  b16x8 af[2][2][2], wf[2][2][2];   // [ping][u][i] — pp static after unroll-2
  GATES_LOADK(0, kbeg);
#pragma unroll 2
  for (int kt = 0; kt < 12; kt++) {           // 12 x BK=64 = 768
    const int pp = kt & 1;
    if (kt < 11) GATES_LOADK(pp ^ 1, kbeg + (kt + 1) * 64);
#pragma unroll
    for (int u = 0; u < 2; u++)
#pragma unroll
      for (int i = 0; i < 2; i++)
#pragma unroll
        for (int j = 0; j < 2; j++)
          acc[i][j] = __builtin_amdgcn_mfma_f32_16x16x32_bf16(af[pp][u][i], wf[pp][u][j], acc[i][j], 0, 0, 0);
  }
#pragma unroll
  for (int i = 0; i < 2; i++)
#pragma unroll
    for (int j = 0; j < 2; j++) {
      const int col = n0 + 16 * j + l;
#pragma unroll
      for (int r = 0; r < 4; r++) {
        const int row = m0 + 16 * i + q * 4 + r;
        gout[(long)row * 2048 + col] = acc[i][j][r];
      }
    }
}

// =========== fused LSTM pointwise + ad-matvec ===========
// 1 block per batch row b. Phase 1: combine 4 split-K gate partials + bias, update c,
// write h_{t+1} (bf16) to h_hist slot AND (bf16-rounded, f32) to LDS. Phase 2:
// ad[b,:] = h@daw^T + dab — each thread two 512-dots, 4-way split accumulators.
__global__ __launch_bounds__(256) void lstm_ad(
    const float* __restrict__ gp, const float* __restrict__ bsum,
    float* __restrict__ c, unsigned short* __restrict__ h_out,
    const unsigned short* __restrict__ daw, const float* __restrict__ dab,
    float* __restrict__ ad_out) {
  const int b = blockIdx.x;
  const int tid = threadIdx.x;
  __shared__ float h_s[512];

#pragma unroll
  for (int u = 0; u < 2; u++) {
    const int d = tid + u * 256;
    float g4[4];
#pragma unroll
    for (int g = 0; g < 4; g++) {
      const int col = g * 512 + d;
      float s = bsum[col];
#pragma unroll
      for (int z = 0; z < 4; z++) s += gp[(long)z * kB * 2048 + (long)b * 2048 + col];
      g4[g] = s;
    }
    const float si = 1.f / (1.f + expf(-g4[0]));
    const float sf = 1.f / (1.f + expf(-g4[1]));
    const float so = 1.f / (1.f + expf(-g4[3]));
    const long idx = (long)b * 512 + d;
    const float cn = sf * c[idx] + si * tanhf(g4[2]);
    const float hn = so * tanhf(cn);
    c[idx] = cn;
    const unsigned short hb = f2bf(hn);
    h_out[idx] = hb;
    h_s[d] = bf2f(hb);              // bf16-rounded value (numerics match bf16-h path)
  }
  __syncthreads();

#pragma unroll
  for (int u = 0; u < 2; u++) {
    const int r = tid + u * 256;
    const unsigned short* wr = daw + (long)r * 512;
    float s0 = 0.f, s1 = 0.f, s2 = 0.f, s3 = 0.f;
#pragma unroll 1
    for (int k = 0; k < 512; k += 32) {
      b16x8 wv[4];
#pragma unroll
      for (int v = 0; v < 4; v++) wv[v] = *(const b16x8*)(wr + k + v * 8);
#pragma unroll
      for (int j = 0; j < 8; j++) s0 += h_s[k + j]      * bf2f(((const unsigned short*)&wv[0])[j]);
#pragma unroll
      for (int j = 0; j < 8; j++) s1 += h_s[k + 8 + j]  * bf2f(((const unsigned short*)&wv[1])[j]);
#pragma unroll
      for (int j = 0; j < 8; j++) s2 += h_s[k + 16 + j] * bf2f(((const unsigned short*)&wv[2])[j]);
#pragma unroll
      for (int j = 0; j < 8; j++) s3 += h_s[k + 24 + j] * bf2f(((const unsigned short*)&wv[3])[j]);
    }
    ad_out[(long)b * 512 + r] = ((s0 + s1) + (s2 + s3)) + dab[r];
  }
}

// =========== prelude kernels ===========
// Fused: read enc f32 once -> write enc_bf AND per-b mean (bf16). grid (kB, 2), 4 dims/thread.
__global__ __launch_bounds__(256) void mean_cvt(
    const float* __restrict__ enc, unsigned short* __restrict__ enc_bf,
    unsigned short* __restrict__ mean_bf) {
  const int b = blockIdx.x;
  const int e = blockIdx.y * 1024 + threadIdx.x * 4;
  const float* base = enc + (long)b * kP * kEnc + e;
  unsigned short* ob = enc_bf + (long)b * kP * kEnc + e;
  f32x4 acc = {};
  int p = 0;
#pragma unroll 1
  for (int it = 0; it < 49; it++, p += 4) {
    f32x4 v[4];
#pragma unroll
    for (int u = 0; u < 4; u++) v[u] = *(const f32x4*)(base + (long)(p + u) * kEnc);
#pragma unroll
    for (int u = 0; u < 4; u++) {
      u16x4 o;
#pragma unroll
      for (int j = 0; j < 4; j++) { acc[j] += v[u][j]; o[j] = f2bf(v[u][j]); }
      *(u16x4*)(ob + (long)(p + u) * kEnc) = o;
    }
  }
  u16x4 om;
#pragma unroll
  for (int j = 0; j < 4; j++) om[j] = f2bf(acc[j] * (1.0f / 196.0f));
  *(u16x4*)(mean_bf + (long)b * kEnc + e) = om;
}

template <bool SRC_BF16>
__global__ __launch_bounds__(256) void mean_kernel(
    const void* __restrict__ enc_, unsigned short* __restrict__ mean_bf) {
  const int b = blockIdx.x;
  const int e = threadIdx.x * 8;
  float acc[8] = {};
  if (SRC_BF16) {
    const unsigned short* base = (const unsigned short*)enc_ + (long)b * kP * kEnc + e;
    for (int p = 0; p < kP; p++) {
      const b16x8 v = *(const b16x8*)(base + (long)p * kEnc);
#pragma unroll
      for (int j = 0; j < 8; j++) acc[j] += bf2f(((const unsigned short*)&v)[j]);
    }
  } else {
    const float* base = (const float*)enc_ + (long)b * kP * kEnc + e;
    for (int p = 0; p < kP; p++) {
      const f32x4 lo = *(const f32x4*)(base + (long)p * kEnc);
      const f32x4 hi = *(const f32x4*)(base + (long)p * kEnc + 4);
#pragma unroll
      for (int j = 0; j < 4; j++) { acc[j] += lo[j]; acc[4 + j] += hi[j]; }
    }
  }
#pragma unroll
  for (int j = 0; j < 8; j++)
    mean_bf[(long)b * kEnc + e + j] = f2bf(acc[j] * (1.0f / 196.0f));
}

__global__ __launch_bounds__(256) void f32_to_bf16_vec(
    const float* __restrict__ src, unsigned short* __restrict__ dst, long n4) {
  for (long i = blockIdx.x * (long)blockDim.x + threadIdx.x; i < n4;
       i += (long)gridDim.x * blockDim.x) {
    const f32x4 v = *(const f32x4*)(src + i * 4);
    u16x4 o;
#pragma unroll
    for (int j = 0; j < 4; j++) o[j] = f2bf(v[j]);
    *(u16x4*)(dst + i * 4) = o;
  }
}

__global__ __launch_bounds__(256) void gather_emb(
    const float* __restrict__ embedding, const int* __restrict__ captions,
    unsigned short* __restrict__ embs) {
  const int r = blockIdx.x;           // t*128 + b
  const int t = r >> 7, b = r & 127;
  const int cap = captions[b * kT + t];
  const float* src = embedding + (long)cap * kEmb;
  unsigned short* dst = embs + (long)r * kEmb;
  for (int i = threadIdx.x; i < kEmb; i += 256) dst[i] = f2bf(src[i]);
}

__global__ void bias_sum_k(const float* __restrict__ b1, const float* __restrict__ b2,
                           float* __restrict__ o) {
  const int i = blockIdx.x * 256 + threadIdx.x;
  if (i < 2048) o[i] = b1[i] + b2[i];
}

// ---------------- host ----------------
extern "C" void kernel_launch(void* const* d_in, const int* in_sizes, int n_in,
                              void* d_out, int out_size, void* d_ws, size_t ws_size,
                              hipStream_t stream) {
  const float* enc = (const float*)d_in[0];
  const int* captions = (const int*)d_in[1];
  const float* embedding = (const float*)d_in[3];
  const float* eaw = (const float*)d_in[4];
  const float* eab = (const float*)d_in[5];
  const float* daw = (const float*)d_in[6];
  const float* dab = (const float*)d_in[7];
  const float* faw = (const float*)d_in[8];
  const float* fab = (const float*)d_in[9];
  const float* Wih = (const float*)d_in[10];
  const float* bih = (const float*)d_in[11];
  const float* Whh = (const float*)d_in[12];
  const float* bhh = (const float*)d_in[13];
  const float* ihw = (const float*)d_in[14];
  const float* ihb = (const float*)d_in[15];
  const float* icw = (const float*)d_in[16];
  const float* icb = (const float*)d_in[17];
  const float* fcw = (const float*)d_in[18];
  const float* fcb = (const float*)d_in[19];

  float* out = (float*)d_out;                        // outputs [B,T,VOCAB]
  float* alphas = out + (long)kB * kT * kVocab;      // alphas  [B,T,P]

  char* ws = (char*)d_ws;
  size_t off = 0;
  auto alloc = [&](size_t bytes) -> void* {
    void* p = ws + off;
    off = (off + bytes + 255) & ~(size_t)255;
    return p;
  };
  unsigned short* attn_enc_bf = (unsigned short*)alloc((size_t)kB * kP * kAttn * 2);
  unsigned short* Wih_bf = (unsigned short*)alloc((size_t)2048 * 2560 * 2);
  unsigned short* Whh_bf = (unsigned short*)alloc((size_t)2048 * 512 * 2);
  unsigned short* fcw_bf = (unsigned short*)alloc((size_t)kVocab * kDec * 2);
  unsigned short* eaw_bf = (unsigned short*)alloc((size_t)kAttn * kEnc * 2);
  unsigned short* daw_bf = (unsigned short*)alloc((size_t)kAttn * kDec * 2);
  unsigned short* ihw_bf = (unsigned short*)alloc((size_t)kDec * kEnc * 2);
  unsigned short* icw_bf = (unsigned short*)alloc((size_t)kDec * kEnc * 2);
  unsigned short* embs_bf = (unsigned short*)alloc((size_t)kT * kB * kEmb * 2);
  unsigned short* mean_bf = (unsigned short*)alloc((size_t)kB * kEnc * 2);
  float* c = (float*)alloc((size_t)kB * kDec * 4);
  // h history: slot 0 = init h; slot t+1 = h after lstm step t (bf16). preds_t uses slot t+1.
  unsigned short* h_hist = (unsigned short*)alloc((size_t)(kT + 1) * kB * kDec * 2);
  float* ad_buf = (float*)alloc((size_t)kB * kAttn * 4);
  unsigned short* ctx_bf = (unsigned short*)alloc((size_t)kB * kEnc * 2);
  float* gates_part = (float*)alloc((size_t)4 * kB * 2048 * 4);
  float* bsum = (float*)alloc((size_t)2048 * 4);
  unsigned short* enc_bf = (unsigned short*)alloc((size_t)kB * kP * kEnc * 2);
  const bool have_enc_bf = (off <= ws_size);

  auto cvt = [&](const float* s, unsigned short* d, long n) {
    const long n4 = n / 4;
    long g = (n4 + 255) / 256;
    if (g > 2048) g = 2048;
    f32_to_bf16_vec<<<dim3((unsigned)g), dim3(256), 0, stream>>>(s, d, n4);
  };

  // ---- prelude
  cvt(eaw, eaw_bf, (long)kAttn * kEnc);
  cvt(daw, daw_bf, (long)kAttn * kDec);
  cvt(Wih, Wih_bf, (long)2048 * 2560);
  cvt(Whh, Whh_bf, (long)2048 * 512);
  cvt(fcw, fcw_bf, (long)kVocab * kDec);
  cvt(ihw, ihw_bf, (long)kDec * kEnc);
  cvt(icw, icw_bf, (long)kDec * kEnc);
  bias_sum_k<<<8, 256, 0, stream>>>(bih, bhh, bsum);
  gather_emb<<<kT * kB, 256, 0, stream>>>(embedding, captions, embs_bf);
  if (have_enc_bf)
    mean_cvt<<<dim3(kB, 2), 256, 0, stream>>>(enc, enc_bf, mean_bf);  // fused cvt + mean
  else
    mean_kernel<false><<<kB, 256, 0, stream>>>(enc, mean_bf);

  // h0 (bf16 direct into h_hist slot 0) and c0
  gemm_bt<true, true><<<dim3(kDec / 64, kB / 64), 256, 0, stream>>>(
      mean_bf, ihw_bf, ihb, (float*)nullptr, h_hist, kB, kDec, kEnc, kDec);
  gemm_bt<true, false><<<dim3(kDec / 64, kB / 64), 256, 0, stream>>>(
      mean_bf, icw_bf, icb, c, (unsigned short*)nullptr, kB, kDec, kEnc, kDec);

  // attn_enc projection: [25088,2048] @ [512,2048]^T -> bf16 [25088,512]
  if (have_enc_bf)
    gemm128<0><<<dim3(kAttn / 128, (kB * kP) / 128), 256, 0, stream>>>(
        enc_bf, eaw_bf, eab, attn_enc_bf, (float*)nullptr, kEnc, kAttn);
  else
    gemm_bt<false, true><<<dim3(kAttn / 64, (kB * kP) / 64), 256, 0, stream>>>(
        enc, eaw_bf, eab, (float*)nullptr, attn_enc_bf, kB * kP, kAttn, kEnc, kAttn);

  // ad for t=0 (h_0)
  adfc_kernel<<<16, 256, 0, stream>>>(h_hist, daw_bf, dab, ad_buf);

  // ---- T sequential decode steps: attn -> gates -> fused lstm+ad (3 kernels/step)
  for (int t = 0; t < kT; t++) {
    const unsigned short* hcur = h_hist + (long)t * kB * kDec;

    if (have_enc_bf)
      attn2<true><<<dim3(kB, 2), 256, 0, stream>>>(
          enc_bf, attn_enc_bf, ad_buf, faw, fab, alphas, ctx_bf, t);
    else
      attn2<false><<<dim3(kB, 2), 256, 0, stream>>>(
          enc, attn_enc_bf, ad_buf, faw, fab, alphas, ctx_bf, t);

    gemm_gates<<<dim3(2048 / 64, kB / 64, 4), 256, 0, stream>>>(
        embs_bf + (long)t * kB * kEmb, ctx_bf, hcur, Wih_bf, Whh_bf, gates_part);

    lstm_ad<<<kB, 256, 0, stream>>>(
        gates_part, bsum, c, h_hist + (long)(t + 1) * kB * kDec, daw_bf, dab, ad_buf);
  }

  // batched preds: [kT*kB, VOCAB] = h_hist[1..20] @ fcw^T + fcb, scattered to out[b,t,:]
  gemm128<1><<<dim3((kVocab + 127) / 128, kT * kB / 128), 256, 0, stream>>>(
      h_hist + (long)kB * kDec, fcw_bf, fcb, (unsigned short*)nullptr, out, kDec, kVocab);
}